// Round 1
// baseline (2293.086 us; speedup 1.0000x reference)
//
#include <hip/hip_runtime.h>

// Gabor filter bank conv: x[16,3,224,224] (as 48 single-ch images), w[512,1,25,25],
// stride 4, pad 12 -> out[16,3,512,56,56]. Cross-correlation (lax.conv semantics).

namespace {
constexpr int NIMG = 48;
constexpr int H = 224, W = 224;
constexpr int OC = 512;
constexpr int KS = 25;
constexpr int ST = 4, PD = 12;
constexpr int HO = 56, WO = 56;

// Tile config: per block 64 channels x (8 rows x 32 cols) outputs.
constexpr int TROWS = 8, TCOLS = 32, TCH = 64;
constexpr int IROWS = (TROWS - 1) * ST + KS;   // 53
constexpr int ICOLS = (TCOLS - 1) * ST + KS;   // 149
constexpr int ISTR  = ICOLS + 2;               // 151 (odd stride breaks pow2 bank strides)
constexpr int RT  = HO / TROWS;                    // 7
constexpr int CT  = (WO + TCOLS - 1) / TCOLS;      // 2 (col tile 1 partially masked)
constexpr int CHT = OC / TCH;                      // 8
constexpr int NBLOCKS = NIMG * CHT * RT * CT;      // 5376
}

__global__ __launch_bounds__(256, 2)
void gabor_conv_kernel(const float* __restrict__ x,
                       const float* __restrict__ wt,
                       float* __restrict__ out) {
    __shared__ float in_lds[IROWS * ISTR];   // ~31.3 KB
    __shared__ float w_lds[TCH * KS];        // 6.4 KB (one ky row of 64 channels)

    const int tid = threadIdx.x;
    int bid = blockIdx.x;
    const int ct  = bid % CT;  bid /= CT;
    const int rt  = bid % RT;  bid /= RT;
    const int cht = bid % CHT; bid /= CHT;
    const int img = bid;                      // 0..47 = b*3 + c

    const int orow0 = rt * TROWS;
    const int ocol0 = ct * TCOLS;
    const int cbase = cht * TCH;
    const int iy0 = orow0 * ST - PD;
    const int ix0 = ocol0 * ST - PD;

    const float* __restrict__ xin = x + (size_t)img * H * W;

    // Stage input tile (zero-fill out of bounds: padding + right/bottom overhang).
    for (int idx = tid; idx < IROWS * ICOLS; idx += 256) {
        int r = idx / ICOLS, c = idx % ICOLS;
        int iy = iy0 + r, ix = ix0 + c;
        float v = 0.0f;
        if (iy >= 0 && iy < H && ix >= 0 && ix < W) v = xin[iy * W + ix];
        in_lds[r * ISTR + c] = v;
    }

    // Thread -> (8 channels, 8 consecutive output cols in one row)
    const int g    = tid & 7;          // channel group: channels cbase + g*8 + [0,8)
    const int pg   = tid >> 3;         // position group 0..31
    const int row  = pg >> 2;          // output row within tile 0..7
    const int colb = (pg & 3) * 8;     // output col base within tile: 0,8,16,24

    float acc[8][8];
    #pragma unroll
    for (int i = 0; i < 8; ++i)
        #pragma unroll
        for (int j = 0; j < 8; ++j) acc[i][j] = 0.0f;

    for (int ky = 0; ky < KS; ++ky) {
        __syncthreads();  // previous iteration's w_lds reads done (also covers in_lds stage)
        for (int idx = tid; idx < TCH * KS; idx += 256) {
            int c = idx / KS, kx = idx % KS;
            w_lds[idx] = wt[(size_t)(cbase + c) * (KS * KS) + ky * KS + kx];
        }
        __syncthreads();

        const float* __restrict__ inrow = &in_lds[(row * ST + ky) * ISTR + colb * ST];
        const float* __restrict__ wrow  = &w_lds[g * 8 * KS];

        #pragma unroll 5
        for (int kx = 0; kx < KS; ++kx) {
            float wv[8], iv[8];
            #pragma unroll
            for (int i = 0; i < 8; ++i) wv[i] = wrow[i * KS + kx];   // wave-broadcast
            #pragma unroll
            for (int j = 0; j < 8; ++j) iv[j] = inrow[j * ST + kx];  // stride-4 floats
            #pragma unroll
            for (int i = 0; i < 8; ++i)
                #pragma unroll
                for (int j = 0; j < 8; ++j)
                    acc[i][j] += wv[i] * iv[j];
        }
    }

    // Store: 8 channels x 8 consecutive cols. 56 % 8 == 0 so the mask is
    // uniform per thread (colb=24 on col-tile 1 is fully out of range).
    const int oy  = orow0 + row;
    const int oxb = ocol0 + colb;
    if (oxb < WO) {
        #pragma unroll
        for (int i = 0; i < 8; ++i) {
            int o = cbase + g * 8 + i;
            float* op = out + (((size_t)img * OC + o) * HO + oy) * WO + oxb;
            float4 v0 = make_float4(acc[i][0], acc[i][1], acc[i][2], acc[i][3]);
            float4 v1 = make_float4(acc[i][4], acc[i][5], acc[i][6], acc[i][7]);
            *reinterpret_cast<float4*>(op)     = v0;
            *reinterpret_cast<float4*>(op + 4) = v1;
        }
    }
}

extern "C" void kernel_launch(void* const* d_in, const int* in_sizes, int n_in,
                              void* d_out, int out_size, void* d_ws, size_t ws_size,
                              hipStream_t stream) {
    const float* x  = (const float*)d_in[0];   // [16,3,224,224]
    const float* wt = (const float*)d_in[1];   // [512,1,25,25]
    float* out = (float*)d_out;                // [16,3,512,56,56]
    (void)in_sizes; (void)n_in; (void)d_ws; (void)ws_size; (void)out_size;

    gabor_conv_kernel<<<NBLOCKS, 256, 0, stream>>>(x, wt, out);
}

// Round 2
// 694.898 us; speedup vs baseline: 3.2999x; 3.2999x over previous
//
#include <hip/hip_runtime.h>
#include <stdint.h>

// Implicit-GEMM Gabor conv via bf16 MFMA.
// x[16,3,224,224] fp32 (48 single-ch images), w[512,1,25,25] fp32,
// stride 4, pad 12 -> out[16,3,512,56,56] fp32.
// Per image: D[512 x 3136] = W[512 x 625] . P[625 x 3136], K split as
// 25 ky-iterations of one 16x16x32 MFMA K-chunk (kx 0..24, padded to 32).

typedef __attribute__((ext_vector_type(8))) short short8v;
typedef __attribute__((ext_vector_type(4))) short short4v;
typedef __attribute__((ext_vector_type(4))) float float4v;

namespace {
constexpr int H = 224, W = 224, OC = 512, KS = 25, ST = 4, PD = 12;
constexpr int HO = 56, WO = 56;
constexpr int TCH = 128;                 // channels per block
constexpr int TOY = 4;                   // output rows per block
constexpr int IR  = (TOY - 1) * ST + KS; // 37 staged input rows
constexpr int IC  = (WO - 1) * ST + 32;  // 252 staged input cols (covers kx-pad reads)
constexpr int ISTR = 260;                // LDS row stride (breaks pow2 banking)
constexpr int KXP = 32;                  // padded kx (K chunk)
constexpr int WSTR = 40;                 // w_lds per-channel stride (80B: bank stride 20)
constexpr int CHT = OC / TCH;            // 4
constexpr int OYT = HO / TOY;            // 14
constexpr int NIMG = 48;
constexpr int NB = NIMG * CHT * OYT;     // 2688 blocks
}

__device__ __forceinline__ short f2bf(float f) {
    uint32_t u = __float_as_uint(f);
    u += 0x7fffu + ((u >> 16) & 1u);     // round-to-nearest-even
    return (short)(u >> 16);
}

__device__ __forceinline__ void stage_w(short* dst, const float* __restrict__ wsrc,
                                        int ky, int tid) {
    // dst layout: [ch][WSTR], kx 0..24 real, 25..31 zero
    #pragma unroll
    for (int i = 0; i < (TCH * KXP) / 256; ++i) {
        int idx = tid + i * 256;
        int ch = idx >> 5, kx = idx & 31;
        float v = (kx < KS) ? wsrc[ch * (KS * KS) + ky * KS + kx] : 0.0f;
        dst[ch * WSTR + kx] = f2bf(v);
    }
}

__global__ __launch_bounds__(256, 2)
void gabor_mfma(const float* __restrict__ x,
                const float* __restrict__ wt,
                float* __restrict__ out) {
    __shared__ __align__(16) short in_lds[IR * ISTR];       // 18.8 KB
    __shared__ __align__(16) short w_lds[2][TCH * WSTR];    // 20 KB

    const int tid = threadIdx.x;
    int bid = blockIdx.x;
    const int oyg = bid % OYT; bid /= OYT;
    const int cht = bid % CHT; bid /= CHT;
    const int img = bid;

    const int oy0 = oyg * TOY;
    const int cbase = cht * TCH;
    const int iy0 = oy0 * ST - PD;
    const float* __restrict__ xin = x + (size_t)img * H * W;
    const float* __restrict__ wsrc = wt + (size_t)cbase * (KS * KS);

    // ---- stage input tile once (fp32 -> bf16, zero-fill OOB) ----
    for (int idx = tid; idx < IR * IC; idx += 256) {
        int r = idx / IC, c = idx % IC;
        int iy = iy0 + r, ix = c - PD;     // col c corresponds to ix = c - PD
        float v = 0.0f;
        if ((unsigned)iy < (unsigned)H && (unsigned)ix < (unsigned)W)
            v = xin[iy * W + ix];
        in_lds[r * ISTR + c] = f2bf(v);
    }
    stage_w(w_lds[0], wsrc, 0, tid);
    __syncthreads();

    // ---- wave / lane mapping ----
    const int lane = tid & 63;
    const int wid  = tid >> 6;
    const int wr = wid >> 1;        // channel half:   wr*64
    const int wc = wid & 1;         // oy row-pair:    oy0 + wc*2
    const int n = lane & 15;        // MFMA col index (position within 16-tile)
    const int q = lane >> 4;        // quad -> k subchunk / D row group
    // position tile (16) = 8 ox  x 2 oy:  ox = b*8 + (n&7), oy = oy0 + wc*2 + (n>>3)
    const int brow0 = (wc * 2 + (n >> 3)) * ST;      // input row base (add ky)
    const int bcol  = (n & 7) * ST + q * 8;          // input col base (add b*32)
    const int awoff = (wr * 64 + n) * WSTR + q * 8;  // A-frag: channel n of tile, kx=q*8..

    float4v acc[4][7];
    #pragma unroll
    for (int a = 0; a < 4; ++a)
        #pragma unroll
        for (int b = 0; b < 7; ++b)
            acc[a][b] = (float4v)0.0f;

    // ---- K loop over ky, weights double-buffered ----
    for (int ky = 0; ky < KS; ++ky) {
        const int cur = ky & 1;
        if (ky + 1 < KS) stage_w(w_lds[cur ^ 1], wsrc, ky + 1, tid);

        const short* __restrict__ inp = &in_lds[(brow0 + ky) * ISTR + bcol];
        short8v B[7];
        #pragma unroll
        for (int b = 0; b < 7; ++b) {
            const short* p = inp + b * 32;           // 8B-aligned
            short4v lo = *(const short4v*)p;
            short4v hi = *(const short4v*)(p + 4);
            B[b] = __builtin_shufflevector(lo, hi, 0, 1, 2, 3, 4, 5, 6, 7);
        }
        const short* __restrict__ wp = &w_lds[cur][awoff];
        #pragma unroll
        for (int a = 0; a < 4; ++a) {
            short8v A = *(const short8v*)(wp + a * 16 * WSTR);  // 16B-aligned
            #pragma unroll
            for (int b = 0; b < 7; ++b)
                acc[a][b] = __builtin_amdgcn_mfma_f32_16x16x32_bf16(A, B[b], acc[a][b], 0, 0, 0);
        }
        __syncthreads();
    }

    // ---- epilogue: D row = q*4 + reg (channel), col = n (position) ----
    const int oy = oy0 + wc * 2 + (n >> 3);
    const int chb = cbase + wr * 64 + q * 4;
    #pragma unroll
    for (int a = 0; a < 4; ++a) {
        #pragma unroll
        for (int b = 0; b < 7; ++b) {
            const int ch = chb + a * 16;
            const int ox = b * 8 + (n & 7);
            float* op = out + (((size_t)img * OC + ch) * HO + oy) * WO + ox;
            float4v v = acc[a][b];
            op[0]            = v[0];
            op[HO * WO]      = v[1];
            op[2 * HO * WO]  = v[2];
            op[3 * HO * WO]  = v[3];
        }
    }
}

extern "C" void kernel_launch(void* const* d_in, const int* in_sizes, int n_in,
                              void* d_out, int out_size, void* d_ws, size_t ws_size,
                              hipStream_t stream) {
    const float* x  = (const float*)d_in[0];   // [16,3,224,224]
    const float* wt = (const float*)d_in[1];   // [512,1,25,25]
    float* out = (float*)d_out;                // [16,3,512,56,56]
    (void)in_sizes; (void)n_in; (void)d_ws; (void)ws_size; (void)out_size;

    gabor_mfma<<<NB, 256, 0, stream>>>(x, wt, out);
}